// Round 1
// baseline (19.688 us; speedup 1.0000x reference)
//
#include <hip/hip_runtime.h>
#include <math.h>

#define H 128          // hidden size
#define NL 3           // layers
#define VOCAB 256

__device__ __forceinline__ float sigmoidf_(float x) {
    return 1.0f / (1.0f + __expf(-x));
}

// One LSTM layer, single timestep, batch 1.
// Grid: 8 blocks x 256 threads. Block b owns hidden units [b*16, b*16+16)
// i.e. gate rows {g*128 + b*16 + j : g in 0..3, j in 0..15} (64 rows).
// 4 threads per row, each a 32-element chunk of the length-128 dots.
__global__ __launch_bounds__(256) void lstm_layer_kernel(
    const float* __restrict__ xin,      // [VOCAB or 1, H]; row selected by x_idx if non-null
    const int*   __restrict__ x_idx,    // nullptr for layers 1,2
    const float* __restrict__ h0,       // [H] this layer's initial hidden
    const float* __restrict__ c0,       // [H]
    const float* __restrict__ w_ih,     // [4H, H] row-major
    const float* __restrict__ w_hh,     // [4H, H]
    const float* __restrict__ b_ih,     // [4H]
    const float* __restrict__ b_hh,     // [4H]
    float* __restrict__ h_out,          // [H]
    float* __restrict__ c_out)          // [H]
{
    __shared__ float s_x[H];
    __shared__ float s_h[H];
    __shared__ float s_red[64][4];
    __shared__ float s_gates[4][16];

    if (x_idx) xin += (size_t)x_idx[0] * H;

    const int t = threadIdx.x;
    if (t < H)      s_x[t] = xin[t];
    else            s_h[t - H] = h0[t - H];
    __syncthreads();

    const int gate_local = t >> 2;        // 0..63
    const int chunk      = t & 3;         // 0..3
    const int g_idx      = gate_local >> 4;   // 0..3 (i,f,g,o)
    const int hu_local   = gate_local & 15;   // 0..15
    const int b          = blockIdx.x;        // 0..7
    const int hu         = b * 16 + hu_local; // 0..127
    const int row        = g_idx * H + hu;    // 0..511

    const float4* wi = (const float4*)(w_ih + (size_t)row * H) + chunk * 8;
    const float4* wh = (const float4*)(w_hh + (size_t)row * H) + chunk * 8;
    const float4* sx = (const float4*)s_x + chunk * 8;
    const float4* sh = (const float4*)s_h + chunk * 8;

    float acc = 0.0f;
#pragma unroll
    for (int i = 0; i < 8; ++i) {
        float4 a  = wi[i];
        float4 xv = sx[i];
        acc = fmaf(a.x, xv.x, acc);
        acc = fmaf(a.y, xv.y, acc);
        acc = fmaf(a.z, xv.z, acc);
        acc = fmaf(a.w, xv.w, acc);
        float4 c2 = wh[i];
        float4 hv = sh[i];
        acc = fmaf(c2.x, hv.x, acc);
        acc = fmaf(c2.y, hv.y, acc);
        acc = fmaf(c2.z, hv.z, acc);
        acc = fmaf(c2.w, hv.w, acc);
    }
    s_red[gate_local][chunk] = acc;
    __syncthreads();

    if (t < 64) {
        const int gi = t >> 4;
        const int hl = t & 15;
        const int r  = gi * H + b * 16 + hl;
        float v = s_red[t][0] + s_red[t][1] + s_red[t][2] + s_red[t][3]
                + b_ih[r] + b_hh[r];
        s_gates[gi][hl] = v;
    }
    __syncthreads();

    if (t < 16) {
        const int hu2 = b * 16 + t;
        const float iv = s_gates[0][t];
        const float fv = s_gates[1][t];
        const float gv = s_gates[2][t];
        const float ov = s_gates[3][t];
        const float c = sigmoidf_(fv) * c0[hu2] + sigmoidf_(iv) * tanhf(gv);
        const float h = sigmoidf_(ov) * tanhf(c);
        c_out[hu2] = c;
        h_out[hu2] = h;
    }
}

// logits[v] = dot(Wd[v], h) + bd[v].  Grid: 4 blocks x 256 threads.
__global__ __launch_bounds__(256) void decoder_kernel(
    const float* __restrict__ h,        // [H]
    const float* __restrict__ Wd,       // [VOCAB, H]
    const float* __restrict__ bd,       // [VOCAB]
    float* __restrict__ logits)         // [VOCAB]
{
    __shared__ float s_h[H];
    __shared__ float s_red[64][4];

    const int t = threadIdx.x;
    if (t < H) s_h[t] = h[t];
    __syncthreads();

    const int out_local = t >> 2;   // 0..63
    const int chunk     = t & 3;    // 0..3
    const int row       = blockIdx.x * 64 + out_local;

    const float4* w  = (const float4*)(Wd + (size_t)row * H) + chunk * 8;
    const float4* sh = (const float4*)s_h + chunk * 8;

    float acc = 0.0f;
#pragma unroll
    for (int i = 0; i < 8; ++i) {
        float4 a  = w[i];
        float4 hv = sh[i];
        acc = fmaf(a.x, hv.x, acc);
        acc = fmaf(a.y, hv.y, acc);
        acc = fmaf(a.z, hv.z, acc);
        acc = fmaf(a.w, hv.w, acc);
    }
    s_red[out_local][chunk] = acc;
    __syncthreads();

    if (t < 64) {
        const int r = blockIdx.x * 64 + t;
        logits[r] = s_red[t][0] + s_red[t][1] + s_red[t][2] + s_red[t][3] + bd[r];
    }
}

extern "C" void kernel_launch(void* const* d_in, const int* in_sizes, int n_in,
                              void* d_out, int out_size, void* d_ws, size_t ws_size,
                              hipStream_t stream) {
    const int*   x    = (const int*)  d_in[0];   // [1]
    const float* h0   = (const float*)d_in[1];   // [3,1,128]
    const float* c0   = (const float*)d_in[2];   // [3,1,128]
    const float* emb  = (const float*)d_in[3];   // [256,128]
    const float* w_ih = (const float*)d_in[4];   // [3,512,128]
    const float* w_hh = (const float*)d_in[5];   // [3,512,128]
    const float* b_ih = (const float*)d_in[6];   // [3,512]
    const float* b_hh = (const float*)d_in[7];   // [3,512]
    const float* Wd   = (const float*)d_in[8];   // [256,128]
    const float* bd   = (const float*)d_in[9];   // [256]

    float* out    = (float*)d_out;
    float* logits = out;            // [256]
    float* hn     = out + VOCAB;    // [3*128]
    float* cn     = hn + NL * H;    // [3*128]

    for (int l = 0; l < NL; ++l) {
        const float* xin   = (l == 0) ? emb : (hn + (l - 1) * H);
        const int*   x_idx = (l == 0) ? x : nullptr;
        lstm_layer_kernel<<<8, 256, 0, stream>>>(
            xin, x_idx,
            h0 + l * H, c0 + l * H,
            w_ih + (size_t)l * 4 * H * H, w_hh + (size_t)l * 4 * H * H,
            b_ih + l * 4 * H, b_hh + l * 4 * H,
            hn + l * H, cn + l * H);
    }
    decoder_kernel<<<4, 256, 0, stream>>>(hn + 2 * H, Wd, bd, logits);
}